// Round 2
// baseline (2553.155 us; speedup 1.0000x reference)
//
#include <hip/hip_runtime.h>

typedef unsigned short u16;
typedef __attribute__((ext_vector_type(8))) short bf16x8;   // 8 bf16 = 4 VGPRs
typedef __attribute__((ext_vector_type(4))) float f32x4;

#define MFMA16(A, B, C) __builtin_amdgcn_mfma_f32_16x16x32_bf16((A), (B), (C), 0, 0, 0)

// tanh(x) = 1 - 2/(e^{2x}+1); exp2-based, saturates correctly at +/-inf
static __device__ __forceinline__ float fast_tanh(float x) {
  float e = __builtin_amdgcn_exp2f(x * 2.8853900817779268f);  // e^(2x)
  return 1.0f - 2.0f * __builtin_amdgcn_rcpf(e + 1.0f);
}
static __device__ __forceinline__ u16 f2bf(float f) {  // RNE fp32->bf16
  unsigned u = __builtin_bit_cast(unsigned, f);
  u += 0x7fffu + ((u >> 16) & 1u);
  return (u16)(u >> 16);
}
static __device__ __forceinline__ float bf2f(u16 h) {
  unsigned u = ((unsigned)h) << 16;
  return __builtin_bit_cast(float, u);
}

// Gather one MFMA B-fragment (16x16x32 bf16): lane (q,c) element j holds
// B[r0 + j][col], r0 = kt*32 + q*8. Works for bf16 or f32 source.
static __device__ __forceinline__ bf16x8 load_bfrag(const void* W, bool isbf,
                                                    int N, int r0, int col) {
  union { bf16x8 v; u16 s[8]; } u;
  if (isbf) {
    const u16* p = (const u16*)W;
#pragma unroll
    for (int j = 0; j < 8; ++j) u.s[j] = p[(r0 + j) * N + col];
  } else {
    const float* p = (const float*)W;
#pragma unroll
    for (int j = 0; j < 8; ++j) u.s[j] = f2bf(p[(r0 + j) * N + col]);
  }
  return u.v;
}

// ---------------------------------------------------------------------------
// Fused NeuralODE: 256 threads = 4 waves. Wave w owns an n-slice:
//   H2(=256)-outputs: cols [64w,64w+64)  (4 n-tiles)
//   H (=128)-outputs: cols [32w,32w+32)  (2 n-tiles)
//   OUT(=64)-outputs: cols [16w,16w+16)  (1 n-tile)
// Batch tile M=32 rows (2 m-tiles). All weight B-frags register-resident,
// gathered directly from global (no workspace). Activations transpose via
// LDS ping-pong (MFMA C-layout write -> A-layout read).
// Input/output dtype (bf16 vs f32) detected at runtime from W_enc bits.
// ---------------------------------------------------------------------------
__global__ __launch_bounds__(256, 1) void node_main(
    const void* __restrict__ xv, void* __restrict__ outv,
    const void* __restrict__ Wenc, const void* __restrict__ benc,
    const void* __restrict__ W1, const void* __restrict__ b1,
    const void* __restrict__ W2, const void* __restrict__ b2,
    const void* __restrict__ W3, const void* __restrict__ b3,
    const void* __restrict__ Wdec, const void* __restrict__ bdec) {
  constexpr int LSTR = 264;  // 256 + 8 pad: keeps b128 alignment, 2-way-max banks
  __shared__ __align__(16) u16 zb[2][32 * LSTR];  // 33792 B

  const int tid = threadIdx.x;
  const int w = tid >> 6, L = tid & 63;
  const int q = L >> 4, c = L & 15;
  const float dt = 0.05f;

  // ---- runtime dtype detection (wave-uniform) ----
  // bf16 world: low u16 of each u32 word of W_enc is a bf16 weight with
  // exponent in [110,124] (|w| in (2^-17, 0.25)) ~always. f32 world: low u16
  // is uniform mantissa bits -> hit prob ~6%. Majority vote separates cleanly.
  int cnt = 0;
  {
    const unsigned* wu = (const unsigned*)Wenc;
#pragma unroll 1
    for (int i = 0; i < 64; ++i) {
      unsigned e = (wu[i] >> 7) & 0xFFu;
      cnt += (e >= 110u && e <= 124u) ? 1 : 0;
    }
  }
  const bool isbf = (cnt >= 32);

  // ---- register-resident weight fragments (per-wave n-slice) ----
  bf16x8 wef[2][2], w1f[4][4], w2f[8][4], w3f[8][2], wdf[4];
#pragma unroll
  for (int kt = 0; kt < 2; ++kt)
#pragma unroll
    for (int n = 0; n < 2; ++n)
      wef[kt][n] = load_bfrag(Wenc, isbf, 128, kt * 32 + q * 8, 32 * w + n * 16 + c);
#pragma unroll
  for (int kt = 0; kt < 4; ++kt)
#pragma unroll
    for (int n = 0; n < 4; ++n)
      w1f[kt][n] = load_bfrag(W1, isbf, 256, kt * 32 + q * 8, 64 * w + n * 16 + c);
#pragma unroll
  for (int kt = 0; kt < 8; ++kt)
#pragma unroll
    for (int n = 0; n < 4; ++n)
      w2f[kt][n] = load_bfrag(W2, isbf, 256, kt * 32 + q * 8, 64 * w + n * 16 + c);
#pragma unroll
  for (int kt = 0; kt < 8; ++kt)
#pragma unroll
    for (int n = 0; n < 2; ++n)
      w3f[kt][n] = load_bfrag(W3, isbf, 128, kt * 32 + q * 8, 32 * w + n * 16 + c);
#pragma unroll
  for (int kt = 0; kt < 4; ++kt)
    wdf[kt] = load_bfrag(Wdec, isbf, 64, kt * 32 + q * 8, 16 * w + c);

  // ---- biases (per-wave slice, fp32) ----
  float b1v[4], b2v[4], b3v[2], bev[2], bdv;
#pragma unroll
  for (int n = 0; n < 4; ++n) {
    int i1 = 64 * w + n * 16 + c;
    b1v[n] = isbf ? bf2f(((const u16*)b1)[i1]) : ((const float*)b1)[i1];
    b2v[n] = isbf ? bf2f(((const u16*)b2)[i1]) : ((const float*)b2)[i1];
  }
#pragma unroll
  for (int n = 0; n < 2; ++n) {
    int i3 = 32 * w + n * 16 + c;
    b3v[n] = isbf ? bf2f(((const u16*)b3)[i3]) : ((const float*)b3)[i3];
    bev[n] = isbf ? bf2f(((const u16*)benc)[i3]) : ((const float*)benc)[i3];
  }
  {
    int id = 16 * w + c;
    bdv = isbf ? bf2f(((const u16*)bdec)[id]) : ((const float*)bdec)[id];
  }

#pragma unroll 1
  for (int tile = blockIdx.x; tile < 2048; tile += 512) {
    const int row0 = tile * 32;

    // ---- encoder: h0 = tanh(x @ Wenc + benc) ----
    f32x4 he[2][2];
#pragma unroll
    for (int mt = 0; mt < 2; ++mt)
#pragma unroll
      for (int n = 0; n < 2; ++n) he[mt][n] = (f32x4){0.f, 0.f, 0.f, 0.f};
#pragma unroll
    for (int kt = 0; kt < 2; ++kt) {
      bf16x8 a[2];
#pragma unroll
      for (int mt = 0; mt < 2; ++mt) {
        const int off = (row0 + mt * 16 + c) * 64 + kt * 32 + q * 8;
        if (isbf) {
          a[mt] = *(const bf16x8*)((const u16*)xv + off);
        } else {
          union { bf16x8 v; u16 s[8]; } u;
          const float* p = (const float*)xv + off;
#pragma unroll
          for (int j = 0; j < 8; ++j) u.s[j] = f2bf(p[j]);
          a[mt] = u.v;
        }
      }
#pragma unroll
      for (int mt = 0; mt < 2; ++mt)
#pragma unroll
        for (int n = 0; n < 2; ++n)
          he[mt][n] = MFMA16(a[mt], wef[kt][n], he[mt][n]);
    }
    float h[2][2][4], r[2][2][4];
#pragma unroll
    for (int mt = 0; mt < 2; ++mt)
#pragma unroll
      for (int n = 0; n < 2; ++n)
#pragma unroll
        for (int i = 0; i < 4; ++i) {
          float v = fast_tanh(he[mt][n][i] + bev[n]);
          h[mt][n][i] = v;
          zb[0][(mt * 16 + q * 4 + i) * LSTR + 32 * w + n * 16 + c] = f2bf(v);
        }
    __syncthreads();

    int p = 0;
#pragma unroll 1
    for (int s = 0; s < 20; ++s) {
#pragma unroll 1
      for (int j = 0; j < 4; ++j) {
        // ---- GEMM1: z1 = tanh(htmp @ W1 + b1), htmp in zb[p] (K=128) ----
        f32x4 acc[2][4];
#pragma unroll
        for (int mt = 0; mt < 2; ++mt)
#pragma unroll
          for (int n = 0; n < 4; ++n) acc[mt][n] = (f32x4){0.f, 0.f, 0.f, 0.f};
#pragma unroll
        for (int kt = 0; kt < 4; ++kt) {
          bf16x8 a[2];
#pragma unroll
          for (int mt = 0; mt < 2; ++mt)
            a[mt] = *(const bf16x8*)&zb[p][(mt * 16 + c) * LSTR + kt * 32 + q * 8];
#pragma unroll
          for (int mt = 0; mt < 2; ++mt)
#pragma unroll
            for (int n = 0; n < 4; ++n)
              acc[mt][n] = MFMA16(a[mt], w1f[kt][n], acc[mt][n]);
        }
#pragma unroll
        for (int mt = 0; mt < 2; ++mt)
#pragma unroll
          for (int n = 0; n < 4; ++n)
#pragma unroll
            for (int i = 0; i < 4; ++i)
              zb[p ^ 1][(mt * 16 + q * 4 + i) * LSTR + 64 * w + n * 16 + c] =
                  f2bf(fast_tanh(acc[mt][n][i] + b1v[n]));
        __syncthreads();

        // ---- GEMM2: z2 = tanh(z1 @ W2 + b2), z1 in zb[p^1] (K=256) ----
#pragma unroll
        for (int mt = 0; mt < 2; ++mt)
#pragma unroll
          for (int n = 0; n < 4; ++n) acc[mt][n] = (f32x4){0.f, 0.f, 0.f, 0.f};
#pragma unroll
        for (int kt = 0; kt < 8; ++kt) {
          bf16x8 a[2];
#pragma unroll
          for (int mt = 0; mt < 2; ++mt)
            a[mt] = *(const bf16x8*)&zb[p ^ 1][(mt * 16 + c) * LSTR + kt * 32 + q * 8];
#pragma unroll
          for (int mt = 0; mt < 2; ++mt)
#pragma unroll
            for (int n = 0; n < 4; ++n)
              acc[mt][n] = MFMA16(a[mt], w2f[kt][n], acc[mt][n]);
        }
#pragma unroll
        for (int mt = 0; mt < 2; ++mt)
#pragma unroll
          for (int n = 0; n < 4; ++n)
#pragma unroll
            for (int i = 0; i < 4; ++i)
              zb[p][(mt * 16 + q * 4 + i) * LSTR + 64 * w + n * 16 + c] =
                  f2bf(fast_tanh(acc[mt][n][i] + b2v[n]));
        __syncthreads();

        // ---- GEMM3: k = z2 @ W3 + b3, z2 in zb[p] (K=256) ----
        f32x4 ak[2][2];
#pragma unroll
        for (int mt = 0; mt < 2; ++mt)
#pragma unroll
          for (int n = 0; n < 2; ++n) ak[mt][n] = (f32x4){0.f, 0.f, 0.f, 0.f};
#pragma unroll
        for (int kt = 0; kt < 8; ++kt) {
          bf16x8 a[2];
#pragma unroll
          for (int mt = 0; mt < 2; ++mt)
            a[mt] = *(const bf16x8*)&zb[p][(mt * 16 + c) * LSTR + kt * 32 + q * 8];
#pragma unroll
          for (int mt = 0; mt < 2; ++mt)
#pragma unroll
            for (int n = 0; n < 2; ++n)
              ak[mt][n] = MFMA16(a[mt], w3f[kt][n], ak[mt][n]);
        }

        // ---- RK4 bookkeeping + write next htmp (bf16) to zb[p^1] ----
        const float wc = (j == 1 || j == 2) ? 2.f : 1.f;
        const float cc = (j == 2) ? dt : 0.5f * dt;
#pragma unroll
        for (int mt = 0; mt < 2; ++mt)
#pragma unroll
          for (int n = 0; n < 2; ++n)
#pragma unroll
            for (int i = 0; i < 4; ++i) {
              float kv = ak[mt][n][i] + b3v[n];
              float rv = (j == 0) ? kv : r[mt][n][i] + wc * kv;
              r[mt][n][i] = rv;
              float ht;
              if (j == 3) {
                h[mt][n][i] += (dt / 6.f) * rv;
                ht = h[mt][n][i];
              } else {
                ht = h[mt][n][i] + cc * kv;
              }
              zb[p ^ 1][(mt * 16 + q * 4 + i) * LSTR + 32 * w + n * 16 + c] = f2bf(ht);
            }
        __syncthreads();
        p ^= 1;
      }
    }

    // ---- decoder: out = hT @ Wdec + bdec, hT (bf16) in zb[p] (K=128) ----
    f32x4 ad[2];
#pragma unroll
    for (int mt = 0; mt < 2; ++mt) ad[mt] = (f32x4){0.f, 0.f, 0.f, 0.f};
#pragma unroll
    for (int kt = 0; kt < 4; ++kt) {
      bf16x8 a[2];
#pragma unroll
      for (int mt = 0; mt < 2; ++mt)
        a[mt] = *(const bf16x8*)&zb[p][(mt * 16 + c) * LSTR + kt * 32 + q * 8];
#pragma unroll
      for (int mt = 0; mt < 2; ++mt)
        ad[mt] = MFMA16(a[mt], wdf[kt], ad[mt]);
    }
#pragma unroll
    for (int mt = 0; mt < 2; ++mt)
#pragma unroll
      for (int i = 0; i < 4; ++i) {
        const int oidx = (row0 + mt * 16 + q * 4 + i) * 64 + 16 * w + c;
        const float v = ad[mt][i] + bdv;
        if (isbf) ((u16*)outv)[oidx] = f2bf(v);
        else      ((float*)outv)[oidx] = v;
      }
    __syncthreads();  // protect zb before next tile's encoder writes
  }
}

extern "C" void kernel_launch(void* const* d_in, const int* in_sizes, int n_in,
                              void* d_out, int out_size, void* d_ws, size_t ws_size,
                              hipStream_t stream) {
  (void)in_sizes; (void)n_in; (void)out_size; (void)d_ws; (void)ws_size;
  node_main<<<512, 256, 0, stream>>>(
      d_in[0], d_out,
      d_in[1], d_in[2],   // W_enc, b_enc
      d_in[3], d_in[4],   // W1, b1
      d_in[5], d_in[6],   // W2, b2
      d_in[7], d_in[8],   // W3, b3
      d_in[9], d_in[10]); // W_dec, b_dec
}

// Round 3
// 1726.602 us; speedup vs baseline: 1.4787x; 1.4787x over previous
//
#include <hip/hip_runtime.h>
#include <hip/hip_bf16.h>

typedef unsigned short u16;
typedef unsigned int u32;
typedef __attribute__((ext_vector_type(8))) short bf16x8;   // 8 bf16 = 4 VGPRs
typedef __attribute__((ext_vector_type(4))) float f32x4;

#define MFMA16(A, B, C) __builtin_amdgcn_mfma_f32_16x16x32_bf16((A), (B), (C), 0, 0, 0)

// tanh(x) = 1 - 2/(e^{2x}+1); exp2-based, saturates correctly at +/-inf
static __device__ __forceinline__ float fast_tanh(float x) {
  float e = __builtin_amdgcn_exp2f(x * 2.8853900817779268f);  // e^(2x)
  return 1.0f - 2.0f * __builtin_amdgcn_rcpf(e + 1.0f);
}
static __device__ __forceinline__ u16 f2bf(float f) {  // RNE fp32->bf16 (scalar path)
  unsigned u = __builtin_bit_cast(unsigned, f);
  u += 0x7fffu + ((u >> 16) & 1u);
  return (u16)(u >> 16);
}
static __device__ __forceinline__ float bf2f(u16 h) {
  unsigned u = ((unsigned)h) << 16;
  return __builtin_bit_cast(float, u);
}
// pack 2 fp32 -> packed bf16x2 (v_cvt_pk_bf16_f32 on gfx950); .x = low u16
static __device__ __forceinline__ u32 pk2(float a, float b) {
  __hip_bfloat162 h = __float22bfloat162_rn(make_float2(a, b));
  union { __hip_bfloat162 h; u32 u; } cv;
  cv.h = h;
  return cv.u;
}

// Gather one MFMA weight fragment: lane (q,c) element j holds W[r0+j][col].
// Used as the A operand (A[m=col][k=r0+j] of W^T) — layout mirror of B-frag.
static __device__ __forceinline__ bf16x8 load_wfrag(const void* W, bool isbf,
                                                    int N, int r0, int col) {
  union { bf16x8 v; u16 s[8]; } u;
  if (isbf) {
    const u16* p = (const u16*)W;
#pragma unroll
    for (int j = 0; j < 8; ++j) u.s[j] = p[(r0 + j) * N + col];
  } else {
    const float* p = (const float*)W;
#pragma unroll
    for (int j = 0; j < 8; ++j) u.s[j] = f2bf(p[(r0 + j) * N + col]);
  }
  return u.v;
}
static __device__ __forceinline__ float ldb(const void* p, bool isbf, int i) {
  return isbf ? bf2f(((const u16*)p)[i]) : ((const float*)p)[i];
}

// ---- swizzled batch-major LDS activation buffer: [batch 32][feature 256] ----
// chunk = 4 u16 (8 B); chunk' = chunk ^ ((batch&7)<<1)  (even XOR keeps b128
// pair adjacency). Writes: b64 (1 chunk), reads: b128 (2 chunks). Both at the
// wave64 bank floor (4 resp. 8 cycles).
static __device__ __forceinline__ void st4(u16* buf, int b, int f0, u32 lo, u32 hi) {
  int ch = ((f0 >> 2) ^ ((b & 7) << 1));
  uint2 v; v.x = lo; v.y = hi;
  *(uint2*)(buf + b * 256 + ch * 4) = v;
}
static __device__ __forceinline__ bf16x8 ld8(const u16* buf, int b, int f0) {
  int ch = ((f0 >> 2) ^ ((b & 7) << 1));  // even
  return *(const bf16x8*)(buf + b * 256 + ch * 4);
}

// ---------------------------------------------------------------------------
// Fused NeuralODE, transposed world: compute z^T = W^T @ h^T per GEMM.
// 512 threads = 8 waves, feature-split: wave w owns H2-feats [32w,32w+32),
// H-feats [16w,16w+16); decoder: wave w -> featOut tile (w>>1), batch half (w&1).
// Batch tile 32 (= 2 MFMA n-tiles). Weights register-resident as A-frags.
// Activations ping-pong through swizzled batch-major LDS (b64 write/b128 read).
// ---------------------------------------------------------------------------
__global__ __launch_bounds__(512, 2) void node_main(
    const void* __restrict__ xv, void* __restrict__ outv,
    const void* __restrict__ Wenc, const void* __restrict__ benc,
    const void* __restrict__ W1, const void* __restrict__ b1,
    const void* __restrict__ W2, const void* __restrict__ b2,
    const void* __restrict__ W3, const void* __restrict__ b3,
    const void* __restrict__ Wdec, const void* __restrict__ bdec) {
  __shared__ __align__(16) u16 zb[2][32 * 256];  // 2 x 16 KB

  const int tid = threadIdx.x;
  const int w = tid >> 6, L = tid & 63;
  const int q = L >> 4, c = L & 15;
  const float dt = 0.05f;

  // ---- runtime dtype detection (uniform): bf16 tensors -> low u16 of u32
  // words of W_enc has bf16-exponent in [110,124] ~always; f32 -> ~6%.
  int cnt = 0;
  {
    const unsigned* wu = (const unsigned*)Wenc;
#pragma unroll 1
    for (int i = 0; i < 64; ++i) {
      unsigned e = (wu[i] >> 7) & 0xFFu;
      cnt += (e >= 110u && e <= 124u) ? 1 : 0;
    }
  }
  const bool isbf = (cnt >= 32);

  // ---- register-resident weight A-frags (per-wave feature slice) ----
  bf16x8 wef[2], w1f[4][2], w2f[8][2], w3f[8], wdf[4];
#pragma unroll
  for (int kt = 0; kt < 2; ++kt)
    wef[kt] = load_wfrag(Wenc, isbf, 128, kt * 32 + q * 8, 16 * w + c);
#pragma unroll
  for (int kt = 0; kt < 4; ++kt)
#pragma unroll
    for (int mt = 0; mt < 2; ++mt)
      w1f[kt][mt] = load_wfrag(W1, isbf, 256, kt * 32 + q * 8, 32 * w + mt * 16 + c);
#pragma unroll
  for (int kt = 0; kt < 8; ++kt)
#pragma unroll
    for (int mt = 0; mt < 2; ++mt)
      w2f[kt][mt] = load_wfrag(W2, isbf, 256, kt * 32 + q * 8, 32 * w + mt * 16 + c);
#pragma unroll
  for (int kt = 0; kt < 8; ++kt)
    w3f[kt] = load_wfrag(W3, isbf, 128, kt * 32 + q * 8, 16 * w + c);
#pragma unroll
  for (int kt = 0; kt < 4; ++kt)
    wdf[kt] = load_wfrag(Wdec, isbf, 64, kt * 32 + q * 8, (w >> 1) * 16 + c);

  // ---- biases, indexed by this lane's feature ROWS (4q+i) ----
  float bev[4], b1v[2][4], b2v[2][4], b3v[4], bdv[4];
#pragma unroll
  for (int i = 0; i < 4; ++i) {
    bev[i] = ldb(benc, isbf, 16 * w + 4 * q + i);
    b3v[i] = ldb(b3, isbf, 16 * w + 4 * q + i);
    bdv[i] = ldb(bdec, isbf, (w >> 1) * 16 + 4 * q + i);
  }
#pragma unroll
  for (int mt = 0; mt < 2; ++mt)
#pragma unroll
    for (int i = 0; i < 4; ++i) {
      b1v[mt][i] = ldb(b1, isbf, 32 * w + mt * 16 + 4 * q + i);
      b2v[mt][i] = ldb(b2, isbf, 32 * w + mt * 16 + 4 * q + i);
    }

#pragma unroll 1
  for (int tile = blockIdx.x; tile < 2048; tile += 512) {
    const int row0 = tile * 32;

    // ---- encoder: h0^T = tanh(Wenc^T @ x^T + benc) ----
    f32x4 he[2];
#pragma unroll
    for (int nt = 0; nt < 2; ++nt)
      he[nt] = (f32x4){bev[0], bev[1], bev[2], bev[3]};
#pragma unroll
    for (int kt = 0; kt < 2; ++kt)
#pragma unroll
      for (int nt = 0; nt < 2; ++nt) {
        bf16x8 a;
        const int off = (row0 + nt * 16 + c) * 64 + kt * 32 + q * 8;
        if (isbf) {
          a = *(const bf16x8*)((const u16*)xv + off);
        } else {
          union { bf16x8 v; u16 s[8]; } u;
          const float* p = (const float*)xv + off;
#pragma unroll
          for (int j = 0; j < 8; ++j) u.s[j] = f2bf(p[j]);
          a = u.v;
        }
        he[nt] = MFMA16(wef[kt], a, he[nt]);
      }
    float h[2][4], r[2][4];
#pragma unroll
    for (int nt = 0; nt < 2; ++nt) {
#pragma unroll
      for (int i = 0; i < 4; ++i) h[nt][i] = fast_tanh(he[nt][i]);
      st4(zb[0], nt * 16 + c, 16 * w + 4 * q,
          pk2(h[nt][0], h[nt][1]), pk2(h[nt][2], h[nt][3]));
    }
    __syncthreads();

    int p = 0;
#pragma unroll 1
    for (int it = 0; it < 80; ++it) {
      const int j = it & 3;

      // ---- GEMM1: z1^T = tanh(W1^T @ htmp^T + b1), htmp in zb[p] (K=128) ----
      f32x4 acc[2][2];
#pragma unroll
      for (int mt = 0; mt < 2; ++mt)
#pragma unroll
        for (int nt = 0; nt < 2; ++nt)
          acc[mt][nt] = (f32x4){b1v[mt][0], b1v[mt][1], b1v[mt][2], b1v[mt][3]};
#pragma unroll
      for (int kt = 0; kt < 4; ++kt) {
        bf16x8 bb[2];
#pragma unroll
        for (int nt = 0; nt < 2; ++nt)
          bb[nt] = ld8(zb[p], nt * 16 + c, kt * 32 + q * 8);
#pragma unroll
        for (int mt = 0; mt < 2; ++mt)
#pragma unroll
          for (int nt = 0; nt < 2; ++nt)
            acc[mt][nt] = MFMA16(w1f[kt][mt], bb[nt], acc[mt][nt]);
      }
#pragma unroll
      for (int mt = 0; mt < 2; ++mt)
#pragma unroll
        for (int nt = 0; nt < 2; ++nt) {
          float t0 = fast_tanh(acc[mt][nt][0]), t1 = fast_tanh(acc[mt][nt][1]);
          float t2 = fast_tanh(acc[mt][nt][2]), t3 = fast_tanh(acc[mt][nt][3]);
          st4(zb[p ^ 1], nt * 16 + c, 32 * w + mt * 16 + 4 * q, pk2(t0, t1), pk2(t2, t3));
        }
      __syncthreads();

      // ---- GEMM2: z2^T = tanh(W2^T @ z1^T + b2), z1 in zb[p^1] (K=256) ----
#pragma unroll
      for (int mt = 0; mt < 2; ++mt)
#pragma unroll
        for (int nt = 0; nt < 2; ++nt)
          acc[mt][nt] = (f32x4){b2v[mt][0], b2v[mt][1], b2v[mt][2], b2v[mt][3]};
#pragma unroll
      for (int kt = 0; kt < 8; ++kt) {
        bf16x8 bb[2];
#pragma unroll
        for (int nt = 0; nt < 2; ++nt)
          bb[nt] = ld8(zb[p ^ 1], nt * 16 + c, kt * 32 + q * 8);
#pragma unroll
        for (int mt = 0; mt < 2; ++mt)
#pragma unroll
          for (int nt = 0; nt < 2; ++nt)
            acc[mt][nt] = MFMA16(w2f[kt][mt], bb[nt], acc[mt][nt]);
      }
#pragma unroll
      for (int mt = 0; mt < 2; ++mt)
#pragma unroll
        for (int nt = 0; nt < 2; ++nt) {
          float t0 = fast_tanh(acc[mt][nt][0]), t1 = fast_tanh(acc[mt][nt][1]);
          float t2 = fast_tanh(acc[mt][nt][2]), t3 = fast_tanh(acc[mt][nt][3]);
          st4(zb[p], nt * 16 + c, 32 * w + mt * 16 + 4 * q, pk2(t0, t1), pk2(t2, t3));
        }
      __syncthreads();

      // ---- GEMM3: k^T = W3^T @ z2^T + b3, z2 in zb[p] (K=256) ----
      f32x4 ak[2];
#pragma unroll
      for (int nt = 0; nt < 2; ++nt)
        ak[nt] = (f32x4){b3v[0], b3v[1], b3v[2], b3v[3]};
#pragma unroll
      for (int kt = 0; kt < 8; ++kt) {
#pragma unroll
        for (int nt = 0; nt < 2; ++nt)
          ak[nt] = MFMA16(w3f[kt], ld8(zb[p], nt * 16 + c, kt * 32 + q * 8), ak[nt]);
      }

      // ---- RK4 bookkeeping + write next htmp^T to zb[p^1] ----
      const float wc = (j == 1 || j == 2) ? 2.f : 1.f;
      const float cc = (j == 2) ? dt : 0.5f * dt;
#pragma unroll
      for (int nt = 0; nt < 2; ++nt) {
        float ht[4];
#pragma unroll
        for (int i = 0; i < 4; ++i) {
          float kv = ak[nt][i];
          float rv = (j == 0) ? kv : r[nt][i] + wc * kv;
          r[nt][i] = rv;
          if (j == 3) {
            h[nt][i] += (dt / 6.f) * rv;
            ht[i] = h[nt][i];
          } else {
            ht[i] = h[nt][i] + cc * kv;
          }
        }
        st4(zb[p ^ 1], nt * 16 + c, 16 * w + 4 * q, pk2(ht[0], ht[1]), pk2(ht[2], ht[3]));
      }
      __syncthreads();
      p ^= 1;
    }

    // ---- decoder: out^T = Wdec^T @ hT^T + bdec, hT in zb[p] (K=128) ----
    f32x4 ad = (f32x4){bdv[0], bdv[1], bdv[2], bdv[3]};
#pragma unroll
    for (int kt = 0; kt < 4; ++kt)
      ad = MFMA16(wdf[kt], ld8(zb[p], (w & 1) * 16 + c, kt * 32 + q * 8), ad);
    {
      const int ob = row0 + (w & 1) * 16 + c;       // batch row
      const int of = (w >> 1) * 16 + 4 * q;         // feature col (4 contiguous)
      if (isbf) {
        uint2 v; v.x = pk2(ad[0], ad[1]); v.y = pk2(ad[2], ad[3]);
        *(uint2*)((u16*)outv + ob * 64 + of) = v;
      } else {
#pragma unroll
        for (int i = 0; i < 4; ++i) ((float*)outv)[ob * 64 + of + i] = ad[i];
      }
    }
    __syncthreads();  // protect zb before next tile's encoder writes
  }
}

extern "C" void kernel_launch(void* const* d_in, const int* in_sizes, int n_in,
                              void* d_out, int out_size, void* d_ws, size_t ws_size,
                              hipStream_t stream) {
  (void)in_sizes; (void)n_in; (void)out_size; (void)d_ws; (void)ws_size;
  node_main<<<512, 512, 0, stream>>>(
      d_in[0], d_out,
      d_in[1], d_in[2],   // W_enc, b_enc
      d_in[3], d_in[4],   // W1, b1
      d_in[5], d_in[6],   // W2, b2
      d_in[7], d_in[8],   // W3, b3
      d_in[9], d_in[10]); // W_dec, b_dec
}

// Round 4
// 1611.874 us; speedup vs baseline: 1.5840x; 1.0712x over previous
//
#include <hip/hip_runtime.h>
#include <hip/hip_bf16.h>

typedef unsigned short u16;
typedef unsigned int u32;
typedef __attribute__((ext_vector_type(8))) short bf16x8;   // 8 bf16 = 4 VGPRs
typedef __attribute__((ext_vector_type(4))) float f32x4;

#define MFMA16(A, B, C) __builtin_amdgcn_mfma_f32_16x16x32_bf16((A), (B), (C), 0, 0, 0)

// tanh(x) = 1 - 2/(e^{2x}+1); exp2-based, saturates correctly at +/-inf
static __device__ __forceinline__ float fast_tanh(float x) {
  float e = __builtin_amdgcn_exp2f(x * 2.8853900817779268f);  // e^(2x)
  return 1.0f - 2.0f * __builtin_amdgcn_rcpf(e + 1.0f);
}
static __device__ __forceinline__ u16 f2bf(float f) {  // RNE fp32->bf16 (scalar)
  unsigned u = __builtin_bit_cast(unsigned, f);
  u += 0x7fffu + ((u >> 16) & 1u);
  return (u16)(u >> 16);
}
static __device__ __forceinline__ float bf2f(u16 h) {
  unsigned u = ((unsigned)h) << 16;
  return __builtin_bit_cast(float, u);
}
// pack 2 fp32 -> packed bf16x2 (v_cvt_pk_bf16_f32 on gfx950); .x = low u16
static __device__ __forceinline__ u32 pk2(float a, float b) {
  __hip_bfloat162 h = __float22bfloat162_rn(make_float2(a, b));
  union { __hip_bfloat162 h; u32 u; } cv;
  cv.h = h;
  return cv.u;
}

// Gather one MFMA weight fragment: lane (q,c) element j holds W[r0+j][col].
// Used as the A operand (A[m=col][k=r0+j] of W^T).
static __device__ __forceinline__ bf16x8 load_wfrag(const void* W, bool isbf,
                                                    int N, int r0, int col) {
  union { bf16x8 v; u16 s[8]; } u;
  if (isbf) {
    const u16* p = (const u16*)W;
#pragma unroll
    for (int j = 0; j < 8; ++j) u.s[j] = p[(r0 + j) * N + col];
  } else {
    const float* p = (const float*)W;
#pragma unroll
    for (int j = 0; j < 8; ++j) u.s[j] = f2bf(p[(r0 + j) * N + col]);
  }
  return u.v;
}
static __device__ __forceinline__ float ldb(const void* p, bool isbf, int i) {
  return isbf ? bf2f(((const u16*)p)[i]) : ((const float*)p)[i];
}

// ---------------------------------------------------------------------------
// Fused NeuralODE, transposed world: z^T = W^T @ h^T per GEMM.
// 512 threads = 8 waves, feature-split: wave w owns H2-feats [32w,32w+32),
// H-feats [16w,16w+16); decoder: wave w -> out-feat tile (w>>1), batch half (w&1).
// Batch tile 32 (2 n-tiles). Weights register/AGPR-resident as A-frags.
// Activations ping-pong through two padded batch-major LDS buffers; all LDS
// addresses are base + constant (ping-pong unrolled at the call sites, no
// swizzle) so they compile to immediate ds offsets.
// ---------------------------------------------------------------------------
__global__ __launch_bounds__(512, 2) void node_main(
    const void* __restrict__ xv, void* __restrict__ outv,
    const void* __restrict__ Wenc, const void* __restrict__ benc,
    const void* __restrict__ W1, const void* __restrict__ b1,
    const void* __restrict__ W2, const void* __restrict__ b2,
    const void* __restrict__ W3, const void* __restrict__ b3,
    const void* __restrict__ Wdec, const void* __restrict__ bdec) {
  constexpr int STR = 264;  // 256 + 8 pad (keeps 16B alignment of fragments)
  __shared__ __align__(16) u16 zb0[32 * STR];
  __shared__ __align__(16) u16 zb1[32 * STR];

  const int tid = threadIdx.x;
  const int w = tid >> 6, L = tid & 63;
  const int q = L >> 4, c = L & 15;
  const float dt = 0.05f;

  // ---- runtime dtype detection (uniform): bf16 -> low u16 of u32 words of
  // W_enc has bf16-exponent in [110,124] ~always; f32 -> ~6%.
  int cnt = 0;
  {
    const unsigned* wu = (const unsigned*)Wenc;
#pragma unroll 1
    for (int i = 0; i < 64; ++i) {
      unsigned e = (wu[i] >> 7) & 0xFFu;
      cnt += (e >= 110u && e <= 124u) ? 1 : 0;
    }
  }
  const bool isbf = (cnt >= 32);

  // ---- register-resident weight A-frags (per-wave feature slice) ----
  bf16x8 wef[2], w1f[4][2], w2f[8][2], w3f[8], wdf[4];
#pragma unroll
  for (int kt = 0; kt < 2; ++kt)
    wef[kt] = load_wfrag(Wenc, isbf, 128, kt * 32 + q * 8, 16 * w + c);
#pragma unroll
  for (int kt = 0; kt < 4; ++kt)
#pragma unroll
    for (int mt = 0; mt < 2; ++mt)
      w1f[kt][mt] = load_wfrag(W1, isbf, 256, kt * 32 + q * 8, 32 * w + mt * 16 + c);
#pragma unroll
  for (int kt = 0; kt < 8; ++kt)
#pragma unroll
    for (int mt = 0; mt < 2; ++mt)
      w2f[kt][mt] = load_wfrag(W2, isbf, 256, kt * 32 + q * 8, 32 * w + mt * 16 + c);
#pragma unroll
  for (int kt = 0; kt < 8; ++kt)
    w3f[kt] = load_wfrag(W3, isbf, 128, kt * 32 + q * 8, 16 * w + c);
#pragma unroll
  for (int kt = 0; kt < 4; ++kt)
    wdf[kt] = load_wfrag(Wdec, isbf, 64, kt * 32 + q * 8, (w >> 1) * 16 + c);

  // ---- biases pre-packed as f32x4 accumulator inits (rows 4q+i) ----
  f32x4 bei, b3i, bdi, b1i[2], b2i[2];
#pragma unroll
  for (int i = 0; i < 4; ++i) {
    bei[i] = ldb(benc, isbf, 16 * w + 4 * q + i);
    b3i[i] = ldb(b3, isbf, 16 * w + 4 * q + i);
    bdi[i] = ldb(bdec, isbf, (w >> 1) * 16 + 4 * q + i);
  }
#pragma unroll
  for (int mt = 0; mt < 2; ++mt)
#pragma unroll
    for (int i = 0; i < 4; ++i) {
      b1i[mt][i] = ldb(b1, isbf, 32 * w + mt * 16 + 4 * q + i);
      b2i[mt][i] = ldb(b2, isbf, 32 * w + mt * 16 + 4 * q + i);
    }

  float h[2][4], r[2][4];  // state: feats 16w+4q+i, batch nt*16+c

  // One f-eval: htmp in A -> z1 in B -> z2 in A -> k (regs) -> htmp' in B.
  auto feval = [&](int j, u16* __restrict__ A, u16* __restrict__ B)
      __attribute__((always_inline)) {
    // ---- GEMM1: z1 = tanh(W1^T @ htmp + b1), K=128 ----
    f32x4 acc[2][2];
#pragma unroll
    for (int mt = 0; mt < 2; ++mt)
#pragma unroll
      for (int nt = 0; nt < 2; ++nt) acc[mt][nt] = b1i[mt];
#pragma unroll
    for (int kt = 0; kt < 4; ++kt) {
      bf16x8 bb0 = *(const bf16x8*)(A + c * STR + kt * 32 + 8 * q);
      bf16x8 bb1 = *(const bf16x8*)(A + (16 + c) * STR + kt * 32 + 8 * q);
#pragma unroll
      for (int mt = 0; mt < 2; ++mt) {
        acc[mt][0] = MFMA16(w1f[kt][mt], bb0, acc[mt][0]);
        acc[mt][1] = MFMA16(w1f[kt][mt], bb1, acc[mt][1]);
      }
    }
#pragma unroll
    for (int mt = 0; mt < 2; ++mt)
#pragma unroll
      for (int nt = 0; nt < 2; ++nt) {
        float t0 = fast_tanh(acc[mt][nt][0]), t1 = fast_tanh(acc[mt][nt][1]);
        float t2 = fast_tanh(acc[mt][nt][2]), t3 = fast_tanh(acc[mt][nt][3]);
        uint2 v; v.x = pk2(t0, t1); v.y = pk2(t2, t3);
        *(uint2*)(B + (nt * 16 + c) * STR + 32 * w + 16 * mt + 4 * q) = v;
      }
    __syncthreads();

    // ---- GEMM2: z2 = tanh(W2^T @ z1 + b2), K=256 ----
#pragma unroll
    for (int mt = 0; mt < 2; ++mt)
#pragma unroll
      for (int nt = 0; nt < 2; ++nt) acc[mt][nt] = b2i[mt];
#pragma unroll
    for (int kt = 0; kt < 8; ++kt) {
      bf16x8 bb0 = *(const bf16x8*)(B + c * STR + kt * 32 + 8 * q);
      bf16x8 bb1 = *(const bf16x8*)(B + (16 + c) * STR + kt * 32 + 8 * q);
#pragma unroll
      for (int mt = 0; mt < 2; ++mt) {
        acc[mt][0] = MFMA16(w2f[kt][mt], bb0, acc[mt][0]);
        acc[mt][1] = MFMA16(w2f[kt][mt], bb1, acc[mt][1]);
      }
    }
#pragma unroll
    for (int mt = 0; mt < 2; ++mt)
#pragma unroll
      for (int nt = 0; nt < 2; ++nt) {
        float t0 = fast_tanh(acc[mt][nt][0]), t1 = fast_tanh(acc[mt][nt][1]);
        float t2 = fast_tanh(acc[mt][nt][2]), t3 = fast_tanh(acc[mt][nt][3]);
        uint2 v; v.x = pk2(t0, t1); v.y = pk2(t2, t3);
        *(uint2*)(A + (nt * 16 + c) * STR + 32 * w + 16 * mt + 4 * q) = v;
      }
    __syncthreads();

    // ---- GEMM3: k = W3^T @ z2 + b3, K=256 ----
    f32x4 ak[2];
    ak[0] = b3i; ak[1] = b3i;
#pragma unroll
    for (int kt = 0; kt < 8; ++kt) {
      bf16x8 bb0 = *(const bf16x8*)(A + c * STR + kt * 32 + 8 * q);
      bf16x8 bb1 = *(const bf16x8*)(A + (16 + c) * STR + kt * 32 + 8 * q);
      ak[0] = MFMA16(w3f[kt], bb0, ak[0]);
      ak[1] = MFMA16(w3f[kt], bb1, ak[1]);
    }

    // ---- RK4 bookkeeping + write next htmp to B (j folds: literal) ----
    const float wc = (j == 1 || j == 2) ? 2.f : 1.f;
    const float cc = (j == 2) ? dt : 0.5f * dt;
#pragma unroll
    for (int nt = 0; nt < 2; ++nt) {
      float ht[4];
#pragma unroll
      for (int i = 0; i < 4; ++i) {
        float kv = ak[nt][i];
        float rv = (j == 0) ? kv : r[nt][i] + wc * kv;
        r[nt][i] = rv;
        if (j == 3) {
          h[nt][i] += (dt / 6.f) * rv;
          ht[i] = h[nt][i];
        } else {
          ht[i] = h[nt][i] + cc * kv;
        }
      }
      uint2 v; v.x = pk2(ht[0], ht[1]); v.y = pk2(ht[2], ht[3]);
      *(uint2*)(B + (nt * 16 + c) * STR + 16 * w + 4 * q) = v;
    }
    __syncthreads();
  };

#pragma unroll 1
  for (int tile = blockIdx.x; tile < 2048; tile += 512) {
    const int row0 = tile * 32;

    // ---- encoder: h0 = tanh(Wenc^T @ x^T + benc) -> regs + zb0 ----
    f32x4 he[2];
    he[0] = bei; he[1] = bei;
#pragma unroll
    for (int kt = 0; kt < 2; ++kt)
#pragma unroll
      for (int nt = 0; nt < 2; ++nt) {
        bf16x8 a;
        const int off = (row0 + nt * 16 + c) * 64 + kt * 32 + q * 8;
        if (isbf) {
          a = *(const bf16x8*)((const u16*)xv + off);
        } else {
          union { bf16x8 v; u16 s[8]; } u;
          const float* p = (const float*)xv + off;
#pragma unroll
          for (int j = 0; j < 8; ++j) u.s[j] = f2bf(p[j]);
          a = u.v;
        }
        he[nt] = MFMA16(wef[kt], a, he[nt]);
      }
#pragma unroll
    for (int nt = 0; nt < 2; ++nt) {
#pragma unroll
      for (int i = 0; i < 4; ++i) h[nt][i] = fast_tanh(he[nt][i]);
      uint2 v; v.x = pk2(h[nt][0], h[nt][1]); v.y = pk2(h[nt][2], h[nt][3]);
      *(uint2*)(zb0 + (nt * 16 + c) * STR + 16 * w + 4 * q) = v;
    }
    __syncthreads();

#pragma unroll 1
    for (int s = 0; s < 20; ++s) {
      feval(0, zb0, zb1);
      feval(1, zb1, zb0);
      feval(2, zb0, zb1);
      feval(3, zb1, zb0);
    }

    // ---- decoder: out = Wdec^T @ hT + bdec, hT in zb0 (K=128) ----
    f32x4 ad = bdi;
#pragma unroll
    for (int kt = 0; kt < 4; ++kt) {
      bf16x8 bb = *(const bf16x8*)(zb0 + ((w & 1) * 16 + c) * STR + kt * 32 + 8 * q);
      ad = MFMA16(wdf[kt], bb, ad);
    }
    {
      const int ob = row0 + (w & 1) * 16 + c;       // batch row
      const int of = (w >> 1) * 16 + 4 * q;         // feature col (4 contiguous)
      if (isbf) {
        uint2 v; v.x = pk2(ad[0], ad[1]); v.y = pk2(ad[2], ad[3]);
        *(uint2*)((u16*)outv + ob * 64 + of) = v;
      } else {
#pragma unroll
        for (int i = 0; i < 4; ++i) ((float*)outv)[ob * 64 + of + i] = ad[i];
      }
    }
    __syncthreads();  // protect zb0 before next tile's encoder writes
  }
}

extern "C" void kernel_launch(void* const* d_in, const int* in_sizes, int n_in,
                              void* d_out, int out_size, void* d_ws, size_t ws_size,
                              hipStream_t stream) {
  (void)in_sizes; (void)n_in; (void)out_size; (void)d_ws; (void)ws_size;
  node_main<<<512, 512, 0, stream>>>(
      d_in[0], d_out,
      d_in[1], d_in[2],   // W_enc, b_enc
      d_in[3], d_in[4],   // W1, b1
      d_in[5], d_in[6],   // W2, b2
      d_in[7], d_in[8],   // W3, b3
      d_in[9], d_in[10]); // W_dec, b_dec
}